// Round 6
// baseline (394.804 us; speedup 1.0000x reference)
//
#include <hip/hip_runtime.h>
#include <hip/hip_bf16.h>

#define B_   8
#define C_   128
#define H_   96
#define W_   96
#define HP_  98            // padded H/W
#define HO_  48
#define N_   2304          // HO_*HO_
#define K_CONV 1152        // C_*9
#define PLANE_IN  9216     // H_*W_
#define TOT_OUT (B_*C_*N_)

typedef __attribute__((ext_vector_type(8))) short          s16x8;
typedef __attribute__((ext_vector_type(8))) unsigned short u16x8;
typedef __attribute__((ext_vector_type(4))) unsigned short u16x4;
typedef __attribute__((ext_vector_type(4))) float          f32x4;

// XOR-swizzled byte offsets for bf16 tiles, 16 B granules
#define SW(row, q)   (((row) << 6) + ((((q) ^ (((row) >> 1) & 3))) << 4))   // 64 B rows (32 k)
#define SW16(row, q) (((row) << 8) + ((((q) ^ ((row) & 15))) << 4))          // 256 B rows (128 k)
#define SW8(row, q)  (((row) << 7) + ((((q) ^ ((row) & 7))) << 4))           // 128 B rows (64 k)

__device__ __forceinline__ ushort f2bf(float f) {
  __hip_bfloat16 h = __float2bfloat16(f);
  return *reinterpret_cast<ushort*>(&h);
}
__device__ __forceinline__ float bf2f(ushort u) {
  return __uint_as_float(((unsigned int)u) << 16);
}

__device__ __forceinline__ float block_reduce_sum_256(float v) {
  #pragma unroll
  for (int o = 32; o > 0; o >>= 1) v += __shfl_down(v, o, 64);
  __shared__ float r[4];
  int lane = threadIdx.x & 63, wv = threadIdx.x >> 6;
  if (lane == 0) r[wv] = v;
  __syncthreads();
  float s = 0.f;
  if (threadIdx.x == 0) s = r[0] + r[1] + r[2] + r[3];
  __syncthreads();
  return s;  // valid on thread 0 only
}

// ---------------- BN param prep ---------------------------------------------
__global__ void k_prep(const float* __restrict__ w, const float* __restrict__ bb,
                       const float* __restrict__ m, const float* __restrict__ v,
                       float* __restrict__ inv, float* __restrict__ beta) {
  int c = threadIdx.x;
  if (c < C_) {
    float iv = w[c] / sqrtf(v[c] + 1e-5f);
    inv[c] = iv;
    beta[c] = bb[c] - m[c] * iv;
  }
}

// ---------------- conv weights fp32 OIHW -> bf16 [co][(kh*3+kw)*128+ci] -----
__global__ __launch_bounds__(256) void k_prep_w(const float* __restrict__ w,
                                                ushort* __restrict__ wb) {
  int id = blockIdx.x * 256 + threadIdx.x;
  if (id >= C_ * K_CONV) return;
  int co = id / K_CONV, rem = id - co * K_CONV;
  int tap = rem >> 7, ci = rem & 127;
  wb[id] = f2bf(w[co * K_CONV + ci * 9 + tap]);
}

// ---------------- x -> 3x padded NHWC bf16 y (BN+ReLU fused) ----------------
__global__ __launch_bounds__(256) void k_prep_y(const float* __restrict__ x,
                                                const float* __restrict__ pinv,
                                                const float* __restrict__ pbeta,
                                                ushort* __restrict__ y0,
                                                ushort* __restrict__ y1,
                                                ushort* __restrict__ y2) {
  const int h1 = blockIdx.x, b = blockIdx.y, t = threadIdx.x;
  ushort* ys[3] = {y0 + (size_t)b * HP_ * HP_ * C_,
                   y1 + (size_t)b * HP_ * HP_ * C_,
                   y2 + (size_t)b * HP_ * HP_ * C_};
  u16x8 zer = (u16x8)0;
  if (h1 == 0 || h1 == HP_ - 1) {
    for (int p = 0; p < 3; ++p)
      for (int g = t; g < HP_ * C_ / 8; g += 256)
        *(u16x8*)(ys[p] + (size_t)h1 * HP_ * C_ + g * 8) = zer;
    return;
  }
  __shared__ float xs[128][97];
  const int h = h1 - 1;
  const float* xb = x + (size_t)b * C_ * PLANE_IN + h * W_;
  for (int id = t; id < 128 * 24; id += 256) {
    int ci = id / 24, w4 = id - ci * 24;
    float4 v = *(const float4*)(xb + (size_t)ci * PLANE_IN + w4 * 4);
    xs[ci][w4 * 4 + 0] = v.x; xs[ci][w4 * 4 + 1] = v.y;
    xs[ci][w4 * 4 + 2] = v.z; xs[ci][w4 * 4 + 3] = v.w;
  }
  __syncthreads();
  if (t < 32) {
    int side = t >> 4, cg = t & 15;
    for (int p = 0; p < 3; ++p)
      *(u16x8*)(ys[p] + ((size_t)h1 * HP_ + (side ? HP_ - 1 : 0)) * C_ + cg * 8) = zer;
  }
  for (int p = 0; p < 3; ++p) {
    const float* inv = pinv + p * 128;
    const float* bet = pbeta + p * 128;
    for (int g = t; g < 96 * 16; g += 256) {
      int wdx = g >> 4, cg = g & 15;
      u16x8 o;
      #pragma unroll
      for (int k = 0; k < 8; ++k) {
        int ci = cg * 8 + k;
        o[k] = f2bf(fmaxf(xs[ci][wdx] * inv[ci] + bet[ci], 0.f));
      }
      *(u16x8*)(ys[p] + ((size_t)h1 * HP_ + (wdx + 1)) * C_ + cg * 8) = o;
    }
  }
}

// ---------------- wx = relu(mean_{hw} x) ------------------------------------
__global__ __launch_bounds__(256) void k_meanx(const float* __restrict__ x,
                                               float* __restrict__ wcat) {
  int bc = blockIdx.x;
  const float* p = x + (size_t)bc * PLANE_IN;
  float s = 0.f;
  for (int i = threadIdx.x; i < PLANE_IN; i += 256) s += p[i];
  s = block_reduce_sum_256(s);
  if (threadIdx.x == 0) {
    int b = bc >> 7, c = bc & 127;
    wcat[b * 256 + c] = fmaxf(s * (1.f / PLANE_IN), 0.f);
  }
}

// ---------------- MFMA implicit-GEMM conv: M=128co x N=64pos x K=1152 -------
// mode 0: out[b][n][c] bf16 (f,g)   mode 1: out[b][c][n] bf16 (h)
__global__ __launch_bounds__(256) void k_conv(const ushort* __restrict__ y_all,
                                              const ushort* __restrict__ wb,
                                              const float* __restrict__ bias,
                                              ushort* __restrict__ out, int mode) {
  __shared__ __align__(16) char smem[16384];
  char* As = smem;          // 128 rows x 64 B (swizzled)
  char* Bs = smem + 8192;   // 64 rows x 64 B (swizzled)
  const int b = blockIdx.z, n0 = blockIdx.x * 64;
  const int t = threadIdx.x, l = t & 63, w = t >> 6;
  const ushort* yb = y_all + (size_t)b * HP_ * HP_ * C_;
  const int pos = t >> 2, q = t & 3;
  const int n_glob = n0 + pos;
  const int oh = n_glob / HO_, ow = n_glob - oh * HO_;
  const int mh = (w & 1) * 64, nh = (w >> 1) * 32;
  f32x4 acc[4][2];
  #pragma unroll
  for (int i = 0; i < 4; ++i)
    #pragma unroll
    for (int j = 0; j < 2; ++j) acc[i][j] = (f32x4)0.f;

  for (int k0 = 0; k0 < K_CONV; k0 += 32) {
    int tap = k0 >> 7, ci0 = k0 & 127;
    int kh = tap / 3, kw = tap - kh * 3;
    #pragma unroll
    for (int g2 = 0; g2 < 2; ++g2) {
      int g = t + g2 * 256, row = g >> 2, qq = g & 3;
      u16x8 d = *(const u16x8*)(wb + row * K_CONV + k0 + qq * 8);
      *(u16x8*)(As + SW(row, qq)) = d;
    }
    {
      int h1 = 2 * oh + kh, w1 = 2 * ow + kw;
      u16x8 d = *(const u16x8*)(yb + ((size_t)h1 * HP_ + w1) * C_ + ci0 + q * 8);
      *(u16x8*)(Bs + SW(pos, q)) = d;
    }
    __syncthreads();
    s16x8 af[4], bf[2];
    #pragma unroll
    for (int i = 0; i < 4; ++i) {
      int r = mh + i * 16 + (l & 15);
      af[i] = *(const s16x8*)(As + SW(r, (l >> 4)));
    }
    #pragma unroll
    for (int j = 0; j < 2; ++j) {
      int r = nh + j * 16 + (l & 15);
      bf[j] = *(const s16x8*)(Bs + SW(r, (l >> 4)));
    }
    #pragma unroll
    for (int i = 0; i < 4; ++i)
      #pragma unroll
      for (int j = 0; j < 2; ++j)
        acc[i][j] = __builtin_amdgcn_mfma_f32_16x16x32_bf16(af[i], bf[j], acc[i][j], 0, 0, 0);
    __syncthreads();
  }

  if (mode == 0) {  // out[b][n][c] via LDS bounce
    ushort* tb = (ushort*)smem;  // [64 pos][128 co]
    #pragma unroll
    for (int i = 0; i < 4; ++i) {
      int co4 = mh + i * 16 + (l >> 4) * 4;
      float4 bi = *(const float4*)&bias[co4];
      float bia[4] = {bi.x, bi.y, bi.z, bi.w};
      #pragma unroll
      for (int j = 0; j < 2; ++j) {
        int pp = nh + j * 16 + (l & 15);
        #pragma unroll
        for (int r = 0; r < 4; ++r)
          tb[pp * 128 + co4 + r] = f2bf(acc[i][j][r] + bia[r]);
      }
    }
    __syncthreads();
    #pragma unroll
    for (int it = 0; it < 4; ++it) {
      int g = t + it * 256;
      int row = g >> 4, gg = g & 15;
      u16x8 d = *(const u16x8*)(tb + row * 128 + gg * 8);
      *(u16x8*)(out + ((size_t)b * N_ + n0 + row) * C_ + gg * 8) = d;
    }
  } else {          // out[b][c][n] via LDS bounce
    ushort* tb = (ushort*)smem;  // [co][64 pos]
    #pragma unroll
    for (int i = 0; i < 4; ++i) {
      int co4 = mh + i * 16 + (l >> 4) * 4;
      float4 bi = *(const float4*)&bias[co4];
      float bia[4] = {bi.x, bi.y, bi.z, bi.w};
      #pragma unroll
      for (int j = 0; j < 2; ++j) {
        int pp = nh + j * 16 + (l & 15);
        #pragma unroll
        for (int r = 0; r < 4; ++r)
          tb[(co4 + r) * 64 + pp] = f2bf(acc[i][j][r] + bia[r]);
      }
    }
    __syncthreads();
    for (int g = t; g < 1024; g += 256) {
      int co = g >> 3, off = (g & 7) * 8;
      u16x8 d = *(const u16x8*)(tb + co * 64 + off);
      *(u16x8*)(out + ((size_t)b * C_ + co) * N_ + n0 + off) = d;
    }
  }
}

// ---------------- pass 1: row stats mx[n], l[n]=sum_m exp(sc-mx) ------------
// scores sc[n][m] = sum_c f[n][c]*g[m][c]; online softmax fold, nothing big stored
__global__ __launch_bounds__(256) void k_stats(const ushort* __restrict__ f,
                                               const ushort* __restrict__ g,
                                               float2* __restrict__ stats) {
  __shared__ __align__(16) char smem[49152];
  char* fs = smem;           // [128 n][128 c] SW16, 32 KB (staged once)
  char* gs = smem + 32768;   // [64 m][128 c] SW16, 16 KB (per m-iter)
  const int b = blockIdx.y, n0 = blockIdx.x * 128;
  const int t = threadIdx.x, l = t & 63, w = t >> 6;
  const int quad = l >> 4;
  const ushort* fb = f + (size_t)b * N_ * C_;
  const ushort* gb = g + (size_t)b * N_ * C_;
  #pragma unroll
  for (int it = 0; it < 8; ++it) {   // fs: 2048 granules
    int G = t + it * 256, row = G >> 4, g16 = G & 15;
    *(u16x8*)(fs + SW16(row, g16)) = *(const u16x8*)(fb + (size_t)(n0 + row) * C_ + g16 * 8);
  }
  float mx_run[2][4], l_run[2][4];
  #pragma unroll
  for (int i = 0; i < 2; ++i)
    #pragma unroll
    for (int r = 0; r < 4; ++r) { mx_run[i][r] = -1e30f; l_run[i][r] = 0.f; }
  s16x8 af[2][4];
  bool af_ok = false;

  for (int m0 = 0; m0 < N_; m0 += 64) {
    #pragma unroll
    for (int it = 0; it < 4; ++it) {   // gs: 1024 granules
      int G = t + it * 256, row = G >> 4, g16 = G & 15;
      *(u16x8*)(gs + SW16(row, g16)) = *(const u16x8*)(gb + (size_t)(m0 + row) * C_ + g16 * 8);
    }
    __syncthreads();
    if (!af_ok) {
      #pragma unroll
      for (int i = 0; i < 2; ++i)
        #pragma unroll
        for (int ks = 0; ks < 4; ++ks)
          af[i][ks] = *(const s16x8*)(fs + SW16((2 * w + i) * 16 + (l & 15), ks * 4 + quad));
      af_ok = true;
    }
    f32x4 acc[2][4];
    #pragma unroll
    for (int i = 0; i < 2; ++i)
      #pragma unroll
      for (int j = 0; j < 4; ++j) acc[i][j] = (f32x4)0.f;
    #pragma unroll
    for (int ks = 0; ks < 4; ++ks) {
      #pragma unroll
      for (int j = 0; j < 4; ++j) {
        s16x8 bf = *(const s16x8*)(gs + SW16(j * 16 + (l & 15), ks * 4 + quad));
        acc[0][j] = __builtin_amdgcn_mfma_f32_16x16x32_bf16(af[0][ks], bf, acc[0][j], 0, 0, 0);
        acc[1][j] = __builtin_amdgcn_mfma_f32_16x16x32_bf16(af[1][ks], bf, acc[1][j], 0, 0, 0);
      }
    }
    __syncthreads();  // gs consumed; safe to restage next iter
    // online fold: rows n = (2w+i)*16 + quad*4 + r ; cols m = j*16 + (l&15)
    #pragma unroll
    for (int i = 0; i < 2; ++i) {
      #pragma unroll
      for (int r = 0; r < 4; ++r) {
        float vmax = fmaxf(fmaxf(acc[i][0][r], acc[i][1][r]),
                           fmaxf(acc[i][2][r], acc[i][3][r]));
        #pragma unroll
        for (int o = 1; o < 16; o <<= 1) vmax = fmaxf(vmax, __shfl_xor(vmax, o, 64));
        float mn = fmaxf(mx_run[i][r], vmax);
        float se = __expf(acc[i][0][r] - mn) + __expf(acc[i][1][r] - mn) +
                   __expf(acc[i][2][r] - mn) + __expf(acc[i][3][r] - mn);
        #pragma unroll
        for (int o = 1; o < 16; o <<= 1) se += __shfl_xor(se, o, 64);
        l_run[i][r] = l_run[i][r] * __expf(mx_run[i][r] - mn) + se;
        mx_run[i][r] = mn;
      }
    }
  }
  if ((l & 15) == 0) {
    #pragma unroll
    for (int i = 0; i < 2; ++i)
      #pragma unroll
      for (int r = 0; r < 4; ++r) {
        int n = n0 + (2 * w + i) * 16 + quad * 4 + r;
        stats[(size_t)b * N_ + n] = make_float2(mx_run[i][r], l_run[i][r]);
      }
  }
}

// ---------------- pass 2: fused scores+softmax+PV ---------------------------
// per (b, m-tile 64): loop n in 64-slabs: sc=f^T g tile; p=exp(sc-mx)/l; s[c][m]+=h[c][n]p[n][m]
__global__ __launch_bounds__(256) void k_attn_out(const ushort* __restrict__ f,
                                                  const ushort* __restrict__ g,
                                                  const ushort* __restrict__ h,
                                                  const float2* __restrict__ stats,
                                                  const float* __restrict__ gammap,
                                                  float* __restrict__ sout) {
  __shared__ __align__(16) char smem[57344];
  char* gs = smem;            // [64 m][128 c] SW16 16 KB (once)
  char* fs = smem + 16384;    // [64 n][128 c] SW16 16 KB (per iter)
  char* hs = smem + 32768;    // [128 c][64 n] SW8 16 KB (per iter)
  char* pT = smem + 49152;    // [64 m][64 n]  SW8  8 KB (per iter)
  const int b = blockIdx.y, m0 = blockIdx.x * 64;
  const int t = threadIdx.x, l = t & 63, w = t >> 6;
  const int quad = l >> 4, lo = l & 15;
  const ushort* fb = f + (size_t)b * N_ * C_;
  const ushort* gb = g + (size_t)b * N_ * C_;
  const ushort* hb = h + (size_t)b * C_ * N_;
  const float2* stb = stats + (size_t)b * N_;
  #pragma unroll
  for (int it = 0; it < 4; ++it) {   // gs: 1024 granules
    int G = t + it * 256, row = G >> 4, g16 = G & 15;
    *(u16x8*)(gs + SW16(row, g16)) = *(const u16x8*)(gb + (size_t)(m0 + row) * C_ + g16 * 8);
  }
  f32x4 accs[2][4];   // PV acc: c rows (2w+i)*16+quad*4+r, m cols j*16+lo
  #pragma unroll
  for (int i = 0; i < 2; ++i)
    #pragma unroll
    for (int j = 0; j < 4; ++j) accs[i][j] = (f32x4)0.f;

  for (int nb = 0; nb < N_; nb += 64) {
    #pragma unroll
    for (int it = 0; it < 4; ++it) {   // fs: 1024 granules
      int G = t + it * 256, row = G >> 4, g16 = G & 15;
      *(u16x8*)(fs + SW16(row, g16)) = *(const u16x8*)(fb + (size_t)(nb + row) * C_ + g16 * 8);
    }
    #pragma unroll
    for (int it = 0; it < 4; ++it) {   // hs: 1024 granules [c][n]
      int G = t + it * 256, row = G >> 3, g8 = G & 7;
      *(u16x8*)(hs + SW8(row, g8)) = *(const u16x8*)(hb + (size_t)row * N_ + nb + g8 * 8);
    }
    __syncthreads();   // SYNC-A: staging done
    // scores: wave w handles n rows w*16..w*16+15 (M-tile = w)
    f32x4 sc[4];
    #pragma unroll
    for (int j = 0; j < 4; ++j) sc[j] = (f32x4)0.f;
    #pragma unroll
    for (int ks = 0; ks < 4; ++ks) {
      s16x8 af = *(const s16x8*)(fs + SW16(w * 16 + lo, ks * 4 + quad));
      #pragma unroll
      for (int j = 0; j < 4; ++j) {
        s16x8 bf = *(const s16x8*)(gs + SW16(j * 16 + lo, ks * 4 + quad));
        sc[j] = __builtin_amdgcn_mfma_f32_16x16x32_bf16(af, bf, sc[j], 0, 0, 0);
      }
    }
    // stats for my 4 n rows (consecutive): n_loc = w*16 + quad*4 + r
    float mxr[4], ilr[4];
    #pragma unroll
    for (int r = 0; r < 4; ++r) {
      float2 st = stb[nb + w * 16 + quad * 4 + r];
      mxr[r] = st.x; ilr[r] = 1.f / st.y;
    }
    // p = exp(sc - mx)*il -> pT[m][n] (bf16, 8 B writes)
    #pragma unroll
    for (int j = 0; j < 4; ++j) {
      u16x4 pv;
      #pragma unroll
      for (int r = 0; r < 4; ++r)
        pv[r] = f2bf(__expf(sc[j][r] - mxr[r]) * ilr[r]);
      int m = j * 16 + lo;
      int nl = w * 16 + quad * 4;           // 4 consecutive n
      *(u16x4*)(pT + SW8(m, nl >> 3) + (nl & 7) * 2) = pv;
    }
    __syncthreads();   // SYNC-B: pT ready
    // PV: D[c][m] += h[c][n]*pT[m][n], K=64 (2 ksteps)
    #pragma unroll
    for (int ks = 0; ks < 2; ++ks) {
      s16x8 ah0 = *(const s16x8*)(hs + SW8((2 * w + 0) * 16 + lo, ks * 4 + quad));
      s16x8 ah1 = *(const s16x8*)(hs + SW8((2 * w + 1) * 16 + lo, ks * 4 + quad));
      #pragma unroll
      for (int j = 0; j < 4; ++j) {
        s16x8 bp = *(const s16x8*)(pT + SW8(j * 16 + lo, ks * 4 + quad));
        accs[0][j] = __builtin_amdgcn_mfma_f32_16x16x32_bf16(ah0, bp, accs[0][j], 0, 0, 0);
        accs[1][j] = __builtin_amdgcn_mfma_f32_16x16x32_bf16(ah1, bp, accs[1][j], 0, 0, 0);
      }
    }
    __syncthreads();   // SYNC-C: all reads done before next restage
  }
  // epilogue: gamma * accs -> sbuf[c][m] fp32, bounce via LDS (stride 68 floats)
  const float gv = gammap[0];
  float* ss = (float*)smem;   // [128 c][68]
  #pragma unroll
  for (int i = 0; i < 2; ++i) {
    int c0 = (2 * w + i) * 16 + quad * 4;
    #pragma unroll
    for (int j = 0; j < 4; ++j) {
      int m = j * 16 + lo;
      #pragma unroll
      for (int r = 0; r < 4; ++r)
        ss[(c0 + r) * 68 + m] = gv * accs[i][j][r];
    }
  }
  __syncthreads();
  #pragma unroll
  for (int it = 0; it < 8; ++it) {   // 2048 float4 groups
    int idx = t + it * 256;
    int c = idx >> 4, mq = idx & 15;
    float4 v = *(const float4*)&ss[c * 68 + mq * 4];
    *(float4*)&sout[((size_t)b * C_ + c) * N_ + m0 + mq * 4] = v;
  }
}

// ---------------- ws = relu(mean_m s) ---------------------------------------
__global__ __launch_bounds__(256) void k_means(const float* __restrict__ s,
                                               float* __restrict__ wcat) {
  int bc = blockIdx.x;
  const float* p = s + (size_t)bc * N_;
  float sm = 0.f;
  for (int i = threadIdx.x; i < N_; i += 256) sm += p[i];
  sm = block_reduce_sum_256(sm);
  if (threadIdx.x == 0) {
    int b = bc >> 7, c = bc & 127;
    wcat[b * 256 + 128 + c] = fmaxf(sm * (1.f / N_), 0.f);
  }
}

// ---------------- SE MLP: 256 -> 42 (relu) -> 128 ---------------------------
__global__ __launch_bounds__(128) void k_se(const float* __restrict__ wcat,
                                            const float* __restrict__ cw,
                                            const float* __restrict__ cb,
                                            const float* __restrict__ uw,
                                            const float* __restrict__ ub,
                                            float* __restrict__ se) {
  const int b = blockIdx.x, t = threadIdx.x;
  __shared__ float wc[256];
  __shared__ float s1[42];
  wc[t] = wcat[b * 256 + t];
  wc[128 + t] = wcat[b * 256 + 128 + t];
  __syncthreads();
  if (t < 42) {
    float a = cb[t];
    const float* r = cw + (size_t)t * 256;
    for (int k = 0; k < 256; ++k) a += wc[k] * r[k];
    s1[t] = fmaxf(a, 0.f);
  }
  __syncthreads();
  {
    float a = ub[t];
    const float* r = uw + (size_t)t * 42;
    for (int j = 0; j < 42; ++j) a += s1[j] * r[j];
    se[b * 128 + t] = a;
  }
}

// ---------------- out = (avgpool2x2(x) + s) * (1 + se) ----------------------
__global__ __launch_bounds__(256) void k_final(const float* __restrict__ x,
                                               const float* __restrict__ s,
                                               const float* __restrict__ se,
                                               float* __restrict__ out) {
  int idx = blockIdx.x * 256 + threadIdx.x;
  if (idx >= TOT_OUT) return;
  int m  = idx % N_;
  int bc = idx / N_;
  int oh = m / HO_, ow = m - oh * HO_;
  const float* xp = x + (size_t)bc * PLANE_IN;
  int ih = oh * 2, iw = ow * 2;
  float l = 0.25f * (xp[ih * W_ + iw] + xp[ih * W_ + iw + 1] +
                     xp[(ih + 1) * W_ + iw] + xp[(ih + 1) * W_ + iw + 1]);
  out[idx] = (l + s[idx]) * (1.f + se[bc]);
}

extern "C" void kernel_launch(void* const* d_in, const int* in_sizes, int n_in,
                              void* d_out, int out_size, void* d_ws, size_t ws_size,
                              hipStream_t stream) {
  (void)in_sizes; (void)n_in; (void)out_size; (void)ws_size;
  const float* x    = (const float*)d_in[0];
  const float* bnw[3] = {(const float*)d_in[1],  (const float*)d_in[7],  (const float*)d_in[13]};
  const float* bnb[3] = {(const float*)d_in[2],  (const float*)d_in[8],  (const float*)d_in[14]};
  const float* bnm[3] = {(const float*)d_in[3],  (const float*)d_in[9],  (const float*)d_in[15]};
  const float* bnv[3] = {(const float*)d_in[4],  (const float*)d_in[10], (const float*)d_in[16]};
  const float* cw_[3] = {(const float*)d_in[5],  (const float*)d_in[11], (const float*)d_in[17]};
  const float* cbb[3] = {(const float*)d_in[6],  (const float*)d_in[12], (const float*)d_in[18]};
  const float* secw = (const float*)d_in[19];
  const float* secb = (const float*)d_in[20];
  const float* seuw = (const float*)d_in[21];
  const float* seub = (const float*)d_in[22];
  const float* gamma = (const float*)d_in[23];
  float* out = (float*)d_out;

  char* ws = (char*)d_ws;
  size_t off = 0;
  auto alloc = [&](size_t bytes) -> char* {
    char* p = ws + off;
    off = (off + bytes + 255) & ~(size_t)255;
    return p;
  };
  ushort* yp[3];
  for (int p = 0; p < 3; ++p) yp[p] = (ushort*)alloc((size_t)B_ * HP_ * HP_ * C_ * 2);
  ushort* wb[3];
  for (int p = 0; p < 3; ++p) wb[p] = (ushort*)alloc((size_t)C_ * K_CONV * 2);
  ushort* fbuf = (ushort*)alloc((size_t)B_ * N_ * C_ * 2);       // [b][n][c]
  ushort* gbuf = (ushort*)alloc((size_t)B_ * N_ * C_ * 2);       // [b][n][c]
  ushort* hbuf = (ushort*)alloc((size_t)B_ * C_ * N_ * 2);       // [b][c][n]
  float2* stats = (float2*)alloc((size_t)B_ * N_ * 8);           // mx, l per row
  float*  sbuf = (float*)alloc((size_t)B_ * C_ * N_ * 4);        // [b][c][n]
  float*  wcat = (float*)alloc(B_ * 256 * 4);
  float*  sebuf = (float*)alloc(B_ * 128 * 4);
  float*  pinv  = (float*)alloc(3 * 128 * 4);
  float*  pbeta = (float*)alloc(3 * 128 * 4);

  for (int p = 0; p < 3; ++p)
    k_prep<<<1, 128, 0, stream>>>(bnw[p], bnb[p], bnm[p], bnv[p], pinv + p * 128, pbeta + p * 128);
  for (int p = 0; p < 3; ++p)
    k_prep_w<<<(C_ * K_CONV + 255) / 256, 256, 0, stream>>>(cw_[p], wb[p]);
  k_prep_y<<<dim3(HP_, B_), 256, 0, stream>>>(x, pinv, pbeta, yp[0], yp[1], yp[2]);

  k_meanx<<<B_ * C_, 256, 0, stream>>>(x, wcat);

  k_conv<<<dim3(N_ / 64, 1, B_), 256, 0, stream>>>(yp[0], wb[0], cbb[0], fbuf, 0);
  k_conv<<<dim3(N_ / 64, 1, B_), 256, 0, stream>>>(yp[1], wb[1], cbb[1], gbuf, 0);
  k_conv<<<dim3(N_ / 64, 1, B_), 256, 0, stream>>>(yp[2], wb[2], cbb[2], hbuf, 1);

  k_stats<<<dim3(N_ / 128, B_), 256, 0, stream>>>(fbuf, gbuf, stats);
  k_attn_out<<<dim3(N_ / 64, B_), 256, 0, stream>>>(fbuf, gbuf, hbuf, stats, gamma, sbuf);

  k_means<<<B_ * C_, 256, 0, stream>>>(sbuf, wcat);
  k_se<<<B_, 128, 0, stream>>>(wcat, secw, secb, seuw, seub, sebuf);

  k_final<<<(TOT_OUT + 255) / 256, 256, 0, stream>>>(x, sbuf, sebuf, out);
}